// Round 5
// baseline (1286.314 us; speedup 1.0000x reference)
//
#include <hip/hip_runtime.h>
#include <math.h>

// NeuromorphicPrivacyNetwork: 3-layer LIF SNN, T=16, B=256, sizes 1024->2048->1024->512.
// Round-5 strategy (round 4 minus the cooperative launch, which silently failed):
//   - 18 regular pipelined dispatches: phase d runs L0(d+1) on 512 blocks | L1(d) on 64 |
//     L2(d-1) on 32 -> 608 blocks (~2.4/CU) so L0 streaming waves hide GEMM latency
//   - GEMM: BK=128 LDS chunks (16/8 iters) + register prefetch overlapping MFMA
//   - W1/W2 preconverted to bf16; spikes stored as bf16 {0,1} (exact)
//   - V-init folded into t==1 branch; out0 written by L2 epilogue at t=16
//   - cost/entropy accumulated online with trailing-window factor min(10, 17-t)

#define B 256
#define T_STEPS 16

typedef short short8 __attribute__((ext_vector_type(8)));
typedef float floatx4 __attribute__((ext_vector_type(4)));

__device__ inline ushort f2bf(float x) {
  unsigned int u = __float_as_uint(x);
  unsigned int r = (u + 0x7FFFu + ((u >> 16) & 1u)) >> 16;
  return (ushort)r;
}
__device__ inline float bf2f(ushort h) {
  return __uint_as_float(((unsigned int)h) << 16);
}
__device__ inline floatx4 mfma16(short8 a, short8 b, floatx4 c) {
  return __builtin_amdgcn_mfma_f32_16x16x32_bf16(a, b, c, 0, 0, 0);
}

// stage 16 fp32 -> hi/lo bf16 pairs into LDS (base0 setup GEMM only)
__device__ inline void stage_split16(const float* __restrict__ src, ushort* dsth, ushort* dstl) {
  float fv[16];
  #pragma unroll
  for (int i = 0; i < 4; ++i) *(float4*)&fv[4 * i] = *(const float4*)(src + 4 * i);
  unsigned int ph[8], pl[8];
  #pragma unroll
  for (int i = 0; i < 8; ++i) {
    ushort h0 = f2bf(fv[2 * i]);
    ushort l0 = f2bf(fv[2 * i] - bf2f(h0));
    ushort h1 = f2bf(fv[2 * i + 1]);
    ushort l1 = f2bf(fv[2 * i + 1] - bf2f(h1));
    ph[i] = (unsigned int)h0 | ((unsigned int)h1 << 16);
    pl[i] = (unsigned int)l0 | ((unsigned int)l1 << 16);
  }
  *(uint4*)dsth       = make_uint4(ph[0], ph[1], ph[2], ph[3]);
  *(uint4*)(dsth + 8) = make_uint4(ph[4], ph[5], ph[6], ph[7]);
  *(uint4*)dstl       = make_uint4(pl[0], pl[1], pl[2], pl[3]);
  *(uint4*)(dstl + 8) = make_uint4(pl[4], pl[5], pl[6], pl[7]);
}

__device__ inline void cost_accum_raw(float csum, int cnt, float* cost, float* tot) {
  #pragma unroll
  for (int off = 32; off > 0; off >>= 1) {
    csum += __shfl_down(csum, off);
    cnt  += __shfl_down(cnt, off);
  }
  __shared__ float sc[4];
  __shared__ int   si[4];
  int wid = threadIdx.x >> 6;
  if ((threadIdx.x & 63) == 0) { sc[wid] = csum; si[wid] = cnt; }
  __syncthreads();
  if (threadIdx.x == 0) {
    float c = sc[0] + sc[1] + sc[2] + sc[3];
    int   k = si[0] + si[1] + si[2] + si[3];
    atomicAdd(cost, c * 0.01f);
    atomicAdd(tot, (float)k);
  }
}

// ---------------- weight row norms (+ cost/tot zeroing) ----------------

__global__ __launch_bounds__(64) void wnorm_kernel(const float* __restrict__ w0,
                                                   const float* __restrict__ w1,
                                                   const float* __restrict__ w2,
                                                   float* __restrict__ wn,
                                                   float* __restrict__ cost,
                                                   float* __restrict__ tot) {
  int r = blockIdx.x;  // 0..3583
  if (r == 0 && threadIdx.x == 0) { *cost = 0.f; *tot = 0.f; }
  const float* row; int K;
  if (r < 2048)      { row = w0 + (size_t)r * 1024;          K = 1024; }
  else if (r < 3072) { row = w1 + (size_t)(r - 2048) * 2048; K = 2048; }
  else               { row = w2 + (size_t)(r - 3072) * 1024; K = 1024; }
  float ss = 0.f;
  for (int k = threadIdx.x; k < K; k += 64) { float x = row[k]; ss += x * x; }
  #pragma unroll
  for (int off = 32; off > 0; off >>= 1) ss += __shfl_down(ss, off);
  if (threadIdx.x == 0) wn[r] = sqrtf(ss);
}

// ---------------- convert W1,W2 -> bf16 ----------------

__global__ __launch_bounds__(256) void convert_w_kernel(const float* __restrict__ w1,
                                                        const float* __restrict__ w2,
                                                        ushort* __restrict__ w1b,
                                                        ushort* __restrict__ w2b) {
  int i = (blockIdx.x * 256 + threadIdx.x) * 8;   // 1280 blocks -> 2621440 elems
  const float* src; ushort* dst;
  if (i < 2097152) { src = w1 + i; dst = w1b + i; }
  else             { src = w2 + (i - 2097152); dst = w2b + (i - 2097152); }
  float4 a = *(const float4*)src;
  float4 b = *(const float4*)(src + 4);
  unsigned int p0 = (unsigned int)f2bf(a.x) | ((unsigned int)f2bf(a.y) << 16);
  unsigned int p1 = (unsigned int)f2bf(a.z) | ((unsigned int)f2bf(a.w) << 16);
  unsigned int p2 = (unsigned int)f2bf(b.x) | ((unsigned int)f2bf(b.y) << 16);
  unsigned int p3 = (unsigned int)f2bf(b.z) | ((unsigned int)f2bf(b.w) << 16);
  *(uint4*)dst = make_uint4(p0, p1, p2, p3);
}

// ---------------- base0 = inputs @ w0^T via split MFMA (one-time) ----------------

__global__ __launch_bounds__(256) void base0_mfma_kernel(const float* __restrict__ A,  // [256][1024]
                                                         const float* __restrict__ W,  // [2048][1024]
                                                         float* __restrict__ C) {      // [256][2048]
  __shared__ ushort Ah[64][72], Al[64][72], Bh[64][72], Bl[64][72];
  const int tid = threadIdx.x;
  const int m0 = blockIdx.x * 64;
  const int n0 = blockIdx.y * 64;
  const int lane = tid & 63, wv = tid >> 6;
  const int wm = wv & 1, wn2 = wv >> 1;
  const int l15 = lane & 15, quad = lane >> 4;
  const int sr = tid >> 2, scol = (tid & 3) * 16;

  floatx4 acc[2][2];
  #pragma unroll
  for (int i = 0; i < 2; ++i)
    #pragma unroll
    for (int j = 0; j < 2; ++j) acc[i][j] = (floatx4){0.f, 0.f, 0.f, 0.f};

  for (int k0 = 0; k0 < 1024; k0 += 64) {
    stage_split16(A + (size_t)(m0 + sr) * 1024 + k0 + scol, &Ah[sr][scol], &Al[sr][scol]);
    stage_split16(W + (size_t)(n0 + sr) * 1024 + k0 + scol, &Bh[sr][scol], &Bl[sr][scol]);
    __syncthreads();
    #pragma unroll
    for (int ks = 0; ks < 2; ++ks) {
      short8 ah[2], al[2], bh[2], bl[2];
      #pragma unroll
      for (int s = 0; s < 2; ++s) {
        ah[s] = *(const short8*)&Ah[32 * wm + 16 * s + l15][ks * 32 + quad * 8];
        al[s] = *(const short8*)&Al[32 * wm + 16 * s + l15][ks * 32 + quad * 8];
        bh[s] = *(const short8*)&Bh[32 * wn2 + 16 * s + l15][ks * 32 + quad * 8];
        bl[s] = *(const short8*)&Bl[32 * wn2 + 16 * s + l15][ks * 32 + quad * 8];
      }
      #pragma unroll
      for (int sm = 0; sm < 2; ++sm)
        #pragma unroll
        for (int sn = 0; sn < 2; ++sn) {
          acc[sm][sn] = mfma16(ah[sm], bh[sn], acc[sm][sn]);
          acc[sm][sn] = mfma16(ah[sm], bl[sn], acc[sm][sn]);
          acc[sm][sn] = mfma16(al[sm], bh[sn], acc[sm][sn]);
        }
    }
    __syncthreads();
  }
  #pragma unroll
  for (int sm = 0; sm < 2; ++sm)
    #pragma unroll
    for (int sn = 0; sn < 2; ++sn)
      #pragma unroll
      for (int r = 0; r < 4; ++r) {
        int m = m0 + 32 * wm + 16 * sm + quad * 4 + r;
        int n = n0 + 32 * wn2 + 16 * sn + l15;
        C[(size_t)m * 2048 + n] = acc[sm][sn][r];
      }
}

// ---------------- params ----------------

struct StepParams {
  const float* base0; const float* cn0; const float* tn0; const float* th0; const float* wn0;
  float* V0; ushort* sp0a; ushort* sp0b;
  const ushort* w1b; const float* cn1; const float* tn1; const float* th1; const float* wn1;
  float* V1; ushort* sp1a; ushort* sp1b;
  const ushort* w2b; const float* cn2; const float* tn2; const float* th2; const float* wn2;
  float* V2; ushort* sp2a; ushort* sp2b;
  float* out; float* cost; float* tot;
};

// ---------------- GEMM+LIF (BK=128 LDS chunks, bf16 W, fused epilogue) ----------------

template<int K, int N, bool LAST>
__device__ void gemm_lif_lds(ushort (*As)[136], ushort (*Bs)[136],
                             const ushort* __restrict__ A,     // [256][K] bf16 spikes
                             const ushort* __restrict__ W,     // [N][K] bf16
                             const ushort* __restrict__ sppr,  // [256][N] prev spikes
                             ushort* __restrict__ spout,       // [256][N]
                             const float* __restrict__ cn, const float* __restrict__ tn,
                             const float* __restrict__ th, const float* __restrict__ wnv,
                             float* __restrict__ V, float* __restrict__ outF,
                             float* cost, float* tot, int t, int bid) {
  const int tid = threadIdx.x;
  const int m0 = (bid & 3) * 64, n0 = (bid >> 2) * 64;
  const int lane = tid & 63, wv = tid >> 6;
  const int wm = wv & 1, wn2 = wv >> 1;
  const int l15 = lane & 15, quad = lane >> 4;
  const int sr = tid >> 2, scol = (tid & 3) * 32;   // each thread: 32 ushorts = 4 uint4

  floatx4 acc[2][2];
  #pragma unroll
  for (int i = 0; i < 2; ++i)
    #pragma unroll
    for (int j = 0; j < 2; ++j) acc[i][j] = (floatx4){0.f, 0.f, 0.f, 0.f};

  const ushort* Ag = A + (size_t)(m0 + sr) * K + scol;
  const ushort* Wg = W + (size_t)(n0 + sr) * K + scol;

  uint4 pa[4], pb[4];
  #pragma unroll
  for (int h = 0; h < 4; ++h) {
    pa[h] = *(const uint4*)(Ag + h * 8);
    pb[h] = *(const uint4*)(Wg + h * 8);
  }

  for (int k0 = 0; k0 < K; k0 += 128) {
    __syncthreads();   // all waves done reading previous chunk's LDS
    #pragma unroll
    for (int h = 0; h < 4; ++h) {
      *(uint4*)&As[sr][scol + h * 8] = pa[h];
      *(uint4*)&Bs[sr][scol + h * 8] = pb[h];
    }
    __syncthreads();
    if (k0 + 128 < K) {   // prefetch next chunk; overlaps MFMA below
      #pragma unroll
      for (int h = 0; h < 4; ++h) {
        pa[h] = *(const uint4*)(Ag + k0 + 128 + h * 8);
        pb[h] = *(const uint4*)(Wg + k0 + 128 + h * 8);
      }
    }
    #pragma unroll
    for (int ks = 0; ks < 4; ++ks) {
      short8 a[2], b[2];
      #pragma unroll
      for (int s = 0; s < 2; ++s) {
        a[s] = *(const short8*)&As[32 * wm + 16 * s + l15][ks * 32 + quad * 8];
        b[s] = *(const short8*)&Bs[32 * wn2 + 16 * s + l15][ks * 32 + quad * 8];
      }
      #pragma unroll
      for (int sm = 0; sm < 2; ++sm)
        #pragma unroll
        for (int sn = 0; sn < 2; ++sn)
          acc[sm][sn] = mfma16(a[sm], b[sn], acc[sm][sn]);
    }
  }

  const float tf = (float)t;
  float csum = 0.f; int cnt = 0;
  #pragma unroll
  for (int sm = 0; sm < 2; ++sm)
    #pragma unroll
    for (int sn = 0; sn < 2; ++sn)
      #pragma unroll
      for (int r = 0; r < 4; ++r) {
        int m = m0 + 32 * wm + 16 * sm + quad * 4 + r;
        int n = n0 + 32 * wn2 + 16 * sn + l15;
        int gi = m * N + n;
        int cb = ((t - 1) * B + m) * N + n;
        float wnn = wnv[n];
        float cur = acc[sm][sn][r] + cn[cb] * (0.05f * wnn);
        float v = (t == 1) ? 0.f : V[gi];
        bool refrac = (t > 1) && (sppr[gi] != 0);
        float Vn = refrac ? v : (0.95f * v + cur);
        float thr = th[n] + tn[cb] * 0.1f;
        bool sp = (!refrac) && (Vn > thr);
        V[gi] = sp ? 0.f : Vn;
        spout[gi] = sp ? (ushort)0x3F80 : (ushort)0;
        if (LAST && t == T_STEPS) outF[gi] = sp ? 1.f : 0.f;
        if (sp) { csum += wnn; cnt++; }
      }
  int f = 17 - t; if (f > 10) f = 10;
  cost_accum_raw(csum * (float)f, cnt, cost, tot);
  (void)tf;
}

// ---------------- L0 elementwise LIF (4 elems/thread) ----------------

__device__ void l0_role(const StepParams& p, int bid, int s) {
  const int tid = threadIdx.x;
  int e = (bid * 256 + tid) * 4;          // 512 blocks cover 524288
  int n0i = e & 2047;
  const ushort* pr = ((s - 1) & 1) ? p.sp0b : p.sp0a;
  ushort* so = (s & 1) ? p.sp0b : p.sp0a;
  size_t off = (size_t)(s - 1) * 524288 + e;

  float4 bb  = *(const float4*)(p.base0 + e);
  float4 c4  = *(const float4*)(p.cn0 + off);
  float4 t4  = *(const float4*)(p.tn0 + off);
  float4 th4 = *(const float4*)(p.th0 + n0i);
  float4 wn4 = *(const float4*)(p.wn0 + n0i);
  float4 vv  = (s == 1) ? make_float4(0.f, 0.f, 0.f, 0.f) : *(const float4*)(p.V0 + e);
  ushort prv[4] = {0, 0, 0, 0};
  if (s > 1) { ushort4 pq = *(const ushort4*)(pr + e); prv[0] = pq.x; prv[1] = pq.y; prv[2] = pq.z; prv[3] = pq.w; }

  float bbv[4] = {bb.x, bb.y, bb.z, bb.w};
  float vvv[4] = {vv.x, vv.y, vv.z, vv.w};
  float cnv[4] = {c4.x, c4.y, c4.z, c4.w};
  float tnv[4] = {t4.x, t4.y, t4.z, t4.w};
  float thv[4] = {th4.x, th4.y, th4.z, th4.w};
  float wnv[4] = {wn4.x, wn4.y, wn4.z, wn4.w};
  float tf = (float)s;
  float csum = 0.f; int cnt = 0;
  ushort sout[4]; float vout[4];
  #pragma unroll
  for (int j = 0; j < 4; ++j) {
    float wnn = wnv[j];
    float cur = bbv[j] + cnv[j] * (0.05f * wnn);
    bool refrac = (s > 1) && (prv[j] != 0);
    float Vn = refrac ? vvv[j] : (0.95f * vvv[j] + cur);
    float thr = thv[j] + tnv[j] * 0.1f;
    bool sp = (!refrac) && (Vn > thr);
    vout[j] = sp ? 0.f : Vn;
    sout[j] = sp ? (ushort)0x3F80 : (ushort)0;
    if (sp) { csum += wnn; cnt++; }
  }
  *(float4*)(p.V0 + e) = make_float4(vout[0], vout[1], vout[2], vout[3]);
  ushort4 sq; sq.x = sout[0]; sq.y = sout[1]; sq.z = sout[2]; sq.w = sout[3];
  *(ushort4*)(so + e) = sq;
  int f = 17 - s; if (f > 10) f = 10;
  cost_accum_raw(csum * (float)f, cnt, p.cost, p.tot);
  (void)tf;
}

// ---------------- pipelined step kernel: L0(d+1) | L1(d) | L2(d-1) ----------------

__global__ __launch_bounds__(256) void step_kernel(StepParams p, int d) {
  __shared__ ushort As[64][136];   // 17408 B
  __shared__ ushort Bs[64][136];   // 17408 B
  const int bid = blockIdx.x;

  if (bid < 512) {
    int s = d + 1;                      // layer 0 at step s
    if (s <= 16) l0_role(p, bid, s);
  } else if (bid < 576) {
    int t = d;                          // layer 1 at step t
    if (t >= 1 && t <= 16) {
      const ushort* A  = (t & 1) ? p.sp0b : p.sp0a;
      const ushort* pr = ((t - 1) & 1) ? p.sp1b : p.sp1a;
      ushort* so       = (t & 1) ? p.sp1b : p.sp1a;
      gemm_lif_lds<2048, 1024, false>(As, Bs, A, p.w1b, pr, so, p.cn1, p.tn1, p.th1, p.wn1,
                                      p.V1, nullptr, p.cost, p.tot, t, bid - 512);
    }
  } else {
    int t2 = d - 1;                     // layer 2 at step t2
    if (t2 >= 1 && t2 <= 16) {
      const ushort* A  = (t2 & 1) ? p.sp1b : p.sp1a;
      const ushort* pr = ((t2 - 1) & 1) ? p.sp2b : p.sp2a;
      ushort* so       = (t2 & 1) ? p.sp2b : p.sp2a;
      gemm_lif_lds<1024, 512, true>(As, Bs, A, p.w2b, pr, so, p.cn2, p.tn2, p.th2, p.wn2,
                                    p.V2, p.out, p.cost, p.tot, t2, bid - 576);
    }
  }
}

// ---------------- finalize ----------------

__global__ __launch_bounds__(64) void finalize_kernel(const float* __restrict__ cost,
                                                      const float* __restrict__ tot,
                                                      float* __restrict__ out) {
  if (threadIdx.x == 0) {
    float c = *cost;
    float p1 = *tot / 14680064.f;   // T*B*(2048+1024+512)
    float p0 = 1.f - p1;
    float ent = -(p1 * log2f(p1 + 1e-12f) + p0 * log2f(p0 + 1e-12f));
    out[131072] = c;
    out[131073] = ent;
  }
}

// ---------------- launch ----------------

extern "C" void kernel_launch(void* const* d_in, const int* in_sizes, int n_in,
                              void* d_out, int out_size, void* d_ws, size_t ws_size,
                              hipStream_t stream) {
  const float* inputs = (const float*)d_in[0];
  const float* w0  = (const float*)d_in[1];
  const float* th0 = (const float*)d_in[2];
  const float* cn0 = (const float*)d_in[3];
  const float* tn0 = (const float*)d_in[4];
  const float* w1  = (const float*)d_in[5];
  const float* th1 = (const float*)d_in[6];
  const float* cn1 = (const float*)d_in[7];
  const float* tn1 = (const float*)d_in[8];
  const float* w2  = (const float*)d_in[9];
  const float* th2 = (const float*)d_in[10];
  const float* cn2 = (const float*)d_in[11];
  const float* tn2 = (const float*)d_in[12];
  float* out = (float*)d_out;
  float* ws  = (float*)d_ws;

  // workspace layout (float slots), total ~3.67M floats = 14.7 MB
  float* wn    = ws;                    // 3584: wn0[2048] wn1[1024] wn2[512]
  float* cost  = ws + 3584;
  float* tot   = ws + 3585;
  float* base0 = ws + 4096;             // 524288
  float* V0    = base0 + 524288;        // 524288
  float* V1    = V0 + 524288;           // 262144
  float* V2    = V1 + 262144;           // 131072
  ushort* w1b  = (ushort*)(V2 + 131072);        // 2097152 ushort
  ushort* w2b  = w1b + 2097152;                 // 524288 ushort
  ushort* sp0a = w2b + 524288;                  // 524288 ushort each
  ushort* sp0b = sp0a + 524288;
  ushort* sp1a = sp0b + 524288;                 // 262144 ushort each
  ushort* sp1b = sp1a + 262144;
  ushort* sp2a = sp1b + 262144;                 // 131072 ushort each
  ushort* sp2b = sp2a + 131072;

  wnorm_kernel<<<3584, 64, 0, stream>>>(w0, w1, w2, wn, cost, tot);
  convert_w_kernel<<<1280, 256, 0, stream>>>(w1, w2, w1b, w2b);
  base0_mfma_kernel<<<dim3(4, 32), 256, 0, stream>>>(inputs, w0, base0);

  StepParams p;
  p.base0 = base0; p.cn0 = cn0; p.tn0 = tn0; p.th0 = th0; p.wn0 = wn;
  p.V0 = V0; p.sp0a = sp0a; p.sp0b = sp0b;
  p.w1b = w1b; p.cn1 = cn1; p.tn1 = tn1; p.th1 = th1; p.wn1 = wn + 2048;
  p.V1 = V1; p.sp1a = sp1a; p.sp1b = sp1b;
  p.w2b = w2b; p.cn2 = cn2; p.tn2 = tn2; p.th2 = th2; p.wn2 = wn + 3072;
  p.V2 = V2; p.sp2a = sp2a; p.sp2b = sp2b;
  p.out = out; p.cost = cost; p.tot = tot;

  for (int d = 0; d <= 17; ++d) {
    step_kernel<<<608, 256, 0, stream>>>(p, d);
  }
  finalize_kernel<<<1, 64, 0, stream>>>(cost, tot, out);
}

// Round 6
// 740.366 us; speedup vs baseline: 1.7374x; 1.7374x over previous
//
#include <hip/hip_runtime.h>
#include <math.h>

// NeuromorphicPrivacyNetwork: 3-layer LIF SNN, T=16, B=256, sizes 1024->2048->1024->512.
// Round-6 strategy: K-split partial GEMMs to break the per-CU-bandwidth serialization
// seen in rounds 3/5 (single 64x64xK block pulled 512KB through one CU's load path).
//   - 20 pipelined dispatches; phase d runs 5 independent roles (all deps cross-dispatch):
//       bid [0,256)   L1-gemm-partial(t=d)    : 4 K-slices x 64 tiles, writes P1[t&1]
//       bid [256,512) L1-lif(t=d-1)           : sum 4 partials + noise -> LIF -> sp1
//       bid [512,640) L2-gemm-partial(t=d-2)  : 4 K-slices x 32 tiles, writes P2
//       bid [640,768) L2-lif(t=d-3)           : LIF -> sp2 (+ out0 at t=16)
//       bid [768,1280) L0-lif(s=d+1)          : elementwise from hoisted base0
//     GEMM roles at LOW bids so they start first (round 5 had L0 starving them).
//   - no LDS in phase kernel (direct-global MFMA fragments) -> zero bank conflicts
//   - W1/W2 bf16; spikes bf16 {0,1}; partials fp32 slice-indexed (no atomics/zeroing)
//   - cost/entropy online with trailing-window factor min(10, 17-t)

#define B 256
#define T_STEPS 16

typedef short short8 __attribute__((ext_vector_type(8)));
typedef float floatx4 __attribute__((ext_vector_type(4)));

__device__ inline ushort f2bf(float x) {
  unsigned int u = __float_as_uint(x);
  unsigned int r = (u + 0x7FFFu + ((u >> 16) & 1u)) >> 16;
  return (ushort)r;
}
__device__ inline float bf2f(ushort h) {
  return __uint_as_float(((unsigned int)h) << 16);
}
__device__ inline floatx4 mfma16(short8 a, short8 b, floatx4 c) {
  return __builtin_amdgcn_mfma_f32_16x16x32_bf16(a, b, c, 0, 0, 0);
}

// stage 16 fp32 -> hi/lo bf16 pairs into LDS (base0 setup GEMM only)
__device__ inline void stage_split16(const float* __restrict__ src, ushort* dsth, ushort* dstl) {
  float fv[16];
  #pragma unroll
  for (int i = 0; i < 4; ++i) *(float4*)&fv[4 * i] = *(const float4*)(src + 4 * i);
  unsigned int ph[8], pl[8];
  #pragma unroll
  for (int i = 0; i < 8; ++i) {
    ushort h0 = f2bf(fv[2 * i]);
    ushort l0 = f2bf(fv[2 * i] - bf2f(h0));
    ushort h1 = f2bf(fv[2 * i + 1]);
    ushort l1 = f2bf(fv[2 * i + 1] - bf2f(h1));
    ph[i] = (unsigned int)h0 | ((unsigned int)h1 << 16);
    pl[i] = (unsigned int)l0 | ((unsigned int)l1 << 16);
  }
  *(uint4*)dsth       = make_uint4(ph[0], ph[1], ph[2], ph[3]);
  *(uint4*)(dsth + 8) = make_uint4(ph[4], ph[5], ph[6], ph[7]);
  *(uint4*)dstl       = make_uint4(pl[0], pl[1], pl[2], pl[3]);
  *(uint4*)(dstl + 8) = make_uint4(pl[4], pl[5], pl[6], pl[7]);
}

__device__ inline void cost_accum_raw(float csum, int cnt, float* cost, float* tot) {
  #pragma unroll
  for (int off = 32; off > 0; off >>= 1) {
    csum += __shfl_down(csum, off);
    cnt  += __shfl_down(cnt, off);
  }
  __shared__ float sc[4];
  __shared__ int   si[4];
  int wid = threadIdx.x >> 6;
  if ((threadIdx.x & 63) == 0) { sc[wid] = csum; si[wid] = cnt; }
  __syncthreads();
  if (threadIdx.x == 0) {
    float c = sc[0] + sc[1] + sc[2] + sc[3];
    int   k = si[0] + si[1] + si[2] + si[3];
    atomicAdd(cost, c * 0.01f);
    atomicAdd(tot, (float)k);
  }
}

// ---------------- weight row norms (+ cost/tot zeroing) ----------------

__global__ __launch_bounds__(64) void wnorm_kernel(const float* __restrict__ w0,
                                                   const float* __restrict__ w1,
                                                   const float* __restrict__ w2,
                                                   float* __restrict__ wn,
                                                   float* __restrict__ cost,
                                                   float* __restrict__ tot) {
  int r = blockIdx.x;  // 0..3583
  if (r == 0 && threadIdx.x == 0) { *cost = 0.f; *tot = 0.f; }
  const float* row; int K;
  if (r < 2048)      { row = w0 + (size_t)r * 1024;          K = 1024; }
  else if (r < 3072) { row = w1 + (size_t)(r - 2048) * 2048; K = 2048; }
  else               { row = w2 + (size_t)(r - 3072) * 1024; K = 1024; }
  float ss = 0.f;
  for (int k = threadIdx.x; k < K; k += 64) { float x = row[k]; ss += x * x; }
  #pragma unroll
  for (int off = 32; off > 0; off >>= 1) ss += __shfl_down(ss, off);
  if (threadIdx.x == 0) wn[r] = sqrtf(ss);
}

// ---------------- convert W1,W2 -> bf16 ----------------

__global__ __launch_bounds__(256) void convert_w_kernel(const float* __restrict__ w1,
                                                        const float* __restrict__ w2,
                                                        ushort* __restrict__ w1b,
                                                        ushort* __restrict__ w2b) {
  int i = (blockIdx.x * 256 + threadIdx.x) * 8;   // 1280 blocks -> 2621440 elems
  const float* src; ushort* dst;
  if (i < 2097152) { src = w1 + i; dst = w1b + i; }
  else             { src = w2 + (i - 2097152); dst = w2b + (i - 2097152); }
  float4 a = *(const float4*)src;
  float4 b = *(const float4*)(src + 4);
  unsigned int p0 = (unsigned int)f2bf(a.x) | ((unsigned int)f2bf(a.y) << 16);
  unsigned int p1 = (unsigned int)f2bf(a.z) | ((unsigned int)f2bf(a.w) << 16);
  unsigned int p2 = (unsigned int)f2bf(b.x) | ((unsigned int)f2bf(b.y) << 16);
  unsigned int p3 = (unsigned int)f2bf(b.z) | ((unsigned int)f2bf(b.w) << 16);
  *(uint4*)dst = make_uint4(p0, p1, p2, p3);
}

// ---------------- base0 = inputs @ w0^T via split MFMA (one-time) ----------------

__global__ __launch_bounds__(256) void base0_mfma_kernel(const float* __restrict__ A,  // [256][1024]
                                                         const float* __restrict__ W,  // [2048][1024]
                                                         float* __restrict__ C) {      // [256][2048]
  __shared__ ushort Ah[64][72], Al[64][72], Bh[64][72], Bl[64][72];
  const int tid = threadIdx.x;
  const int m0 = blockIdx.x * 64;
  const int n0 = blockIdx.y * 64;
  const int lane = tid & 63, wv = tid >> 6;
  const int wm = wv & 1, wn2 = wv >> 1;
  const int l15 = lane & 15, quad = lane >> 4;
  const int sr = tid >> 2, scol = (tid & 3) * 16;

  floatx4 acc[2][2];
  #pragma unroll
  for (int i = 0; i < 2; ++i)
    #pragma unroll
    for (int j = 0; j < 2; ++j) acc[i][j] = (floatx4){0.f, 0.f, 0.f, 0.f};

  for (int k0 = 0; k0 < 1024; k0 += 64) {
    stage_split16(A + (size_t)(m0 + sr) * 1024 + k0 + scol, &Ah[sr][scol], &Al[sr][scol]);
    stage_split16(W + (size_t)(n0 + sr) * 1024 + k0 + scol, &Bh[sr][scol], &Bl[sr][scol]);
    __syncthreads();
    #pragma unroll
    for (int ks = 0; ks < 2; ++ks) {
      short8 ah[2], al[2], bh[2], bl[2];
      #pragma unroll
      for (int s = 0; s < 2; ++s) {
        ah[s] = *(const short8*)&Ah[32 * wm + 16 * s + l15][ks * 32 + quad * 8];
        al[s] = *(const short8*)&Al[32 * wm + 16 * s + l15][ks * 32 + quad * 8];
        bh[s] = *(const short8*)&Bh[32 * wn2 + 16 * s + l15][ks * 32 + quad * 8];
        bl[s] = *(const short8*)&Bl[32 * wn2 + 16 * s + l15][ks * 32 + quad * 8];
      }
      #pragma unroll
      for (int sm = 0; sm < 2; ++sm)
        #pragma unroll
        for (int sn = 0; sn < 2; ++sn) {
          acc[sm][sn] = mfma16(ah[sm], bh[sn], acc[sm][sn]);
          acc[sm][sn] = mfma16(ah[sm], bl[sn], acc[sm][sn]);
          acc[sm][sn] = mfma16(al[sm], bh[sn], acc[sm][sn]);
        }
    }
    __syncthreads();
  }
  #pragma unroll
  for (int sm = 0; sm < 2; ++sm)
    #pragma unroll
    for (int sn = 0; sn < 2; ++sn)
      #pragma unroll
      for (int r = 0; r < 4; ++r) {
        int m = m0 + 32 * wm + 16 * sm + quad * 4 + r;
        int n = n0 + 32 * wn2 + 16 * sn + l15;
        C[(size_t)m * 2048 + n] = acc[sm][sn][r];
      }
}

// ---------------- params ----------------

struct StepParams {
  const float* base0; const float* cn0; const float* tn0; const float* th0; const float* wn0;
  float* V0; ushort* sp0a; ushort* sp0b;
  const ushort* w1b; const float* cn1; const float* tn1; const float* th1; const float* wn1;
  float* V1; ushort* sp1a; ushort* sp1b;
  const ushort* w2b; const float* cn2; const float* tn2; const float* th2; const float* wn2;
  float* V2; ushort* sp2a; ushort* sp2b;
  float* P1; float* P2;   // fp32 partials: P1[2][4][256][1024], P2[2][4][256][512]
  float* out; float* cost; float* tot;
};

// ---------------- partial GEMM: 64x64 tile over one K-slice, direct-global frags ----------

template<int K>
__device__ inline void ld_frags(const ushort* __restrict__ Abase,
                                const ushort* __restrict__ Wbase,
                                int l15, int k0, uint4 fa[2][2], uint4 fb[2][2]) {
  #pragma unroll
  for (int ks = 0; ks < 2; ++ks)
    #pragma unroll
    for (int s = 0; s < 2; ++s) {
      fa[ks][s] = *(const uint4*)(Abase + (size_t)(16 * s + l15) * K + k0 + ks * 32);
      fb[ks][s] = *(const uint4*)(Wbase + (size_t)(16 * s + l15) * K + k0 + ks * 32);
    }
}

template<int K, int N>
__device__ void gemm_partial(const ushort* __restrict__ A,   // [256][K] bf16 spikes
                             const ushort* __restrict__ W,   // [N][K] bf16
                             float* __restrict__ P,          // [4][256][N] fp32 (this parity)
                             int tile, int slice) {
  constexpr int SL = K / 4;           // K-slice length
  const int ks0 = slice * SL;
  const int tid = threadIdx.x;
  const int m0 = (tile & 3) * 64, n0 = (tile >> 2) * 64;
  const int lane = tid & 63, wv = tid >> 6;
  const int wm = wv & 1, wn2 = wv >> 1;
  const int l15 = lane & 15, quad = lane >> 4;

  const ushort* Abase = A + (size_t)(m0 + 32 * wm) * K + ks0 + quad * 8;
  const ushort* Wbase = W + (size_t)(n0 + 32 * wn2) * K + ks0 + quad * 8;

  floatx4 acc[2][2];
  #pragma unroll
  for (int i = 0; i < 2; ++i)
    #pragma unroll
    for (int j = 0; j < 2; ++j) acc[i][j] = (floatx4){0.f, 0.f, 0.f, 0.f};

  uint4 fa[2][2], fb[2][2];
  ld_frags<K>(Abase, Wbase, l15, 0, fa, fb);
  for (int k0 = 0; k0 < SL; k0 += 64) {
    uint4 na[2][2], nb[2][2];
    if (k0 + 64 < SL) ld_frags<K>(Abase, Wbase, l15, k0 + 64, na, nb);
    #pragma unroll
    for (int ks = 0; ks < 2; ++ks)
      #pragma unroll
      for (int sm = 0; sm < 2; ++sm)
        #pragma unroll
        for (int sn = 0; sn < 2; ++sn)
          acc[sm][sn] = mfma16(*(const short8*)&fa[ks][sm], *(const short8*)&fb[ks][sn], acc[sm][sn]);
    #pragma unroll
    for (int ks = 0; ks < 2; ++ks)
      #pragma unroll
      for (int s = 0; s < 2; ++s) { fa[ks][s] = na[ks][s]; fb[ks][s] = nb[ks][s]; }
  }

  float* Ps = P + (size_t)slice * 256 * N;
  #pragma unroll
  for (int sm = 0; sm < 2; ++sm)
    #pragma unroll
    for (int sn = 0; sn < 2; ++sn)
      #pragma unroll
      for (int r = 0; r < 4; ++r) {
        int m = m0 + 32 * wm + 16 * sm + quad * 4 + r;
        int n = n0 + 32 * wn2 + 16 * sn + l15;
        Ps[(size_t)m * N + n] = acc[sm][sn][r];
      }
}

// ---------------- LIF from 4 fp32 partials + noise ----------------

template<int N, bool LAST>
__device__ void lif_partial(const float* __restrict__ P,     // [4][256][N] (this parity)
                            const ushort* __restrict__ sppr, // [256][N] prev spikes
                            ushort* __restrict__ spout,      // [256][N]
                            const float* __restrict__ cn, const float* __restrict__ tn,
                            const float* __restrict__ th, const float* __restrict__ wnv,
                            float* __restrict__ V, float* __restrict__ outF,
                            float* cost, float* tot, int t, int bid) {
  constexpr int SZ = 256 * N;
  int e = (bid * 256 + threadIdx.x) * 4;
  int n = e & (N - 1);
  size_t off = (size_t)(t - 1) * SZ + e;

  float4 a0 = *(const float4*)(P + e);
  float4 a1 = *(const float4*)(P + SZ + e);
  float4 a2 = *(const float4*)(P + 2 * SZ + e);
  float4 a3 = *(const float4*)(P + 3 * SZ + e);
  float4 c4  = *(const float4*)(cn + off);
  float4 t4  = *(const float4*)(tn + off);
  float4 th4 = *(const float4*)(th + n);
  float4 wn4 = *(const float4*)(wnv + n);
  float4 vv  = (t == 1) ? make_float4(0.f, 0.f, 0.f, 0.f) : *(const float4*)(V + e);
  ushort prv[4] = {0, 0, 0, 0};
  if (t > 1) { ushort4 pq = *(const ushort4*)(sppr + e); prv[0] = pq.x; prv[1] = pq.y; prv[2] = pq.z; prv[3] = pq.w; }

  float accv[4] = {a0.x + a1.x + a2.x + a3.x, a0.y + a1.y + a2.y + a3.y,
                   a0.z + a1.z + a2.z + a3.z, a0.w + a1.w + a2.w + a3.w};
  float vvv[4] = {vv.x, vv.y, vv.z, vv.w};
  float cnv[4] = {c4.x, c4.y, c4.z, c4.w};
  float tnv[4] = {t4.x, t4.y, t4.z, t4.w};
  float thv[4] = {th4.x, th4.y, th4.z, th4.w};
  float wnq[4] = {wn4.x, wn4.y, wn4.z, wn4.w};
  float tf = (float)t;
  float csum = 0.f; int cnt = 0;
  ushort sout[4]; float vout[4]; float oout[4];
  #pragma unroll
  for (int j = 0; j < 4; ++j) {
    float wnn = wnq[j];
    float cur = accv[j] + cnv[j] * (0.05f * wnn);
    bool refrac = (t > 1) && (prv[j] != 0);
    float Vn = refrac ? vvv[j] : (0.95f * vvv[j] + cur);
    float thr = thv[j] + tnv[j] * 0.1f;
    bool sp = (!refrac) && (Vn > thr);
    vout[j] = sp ? 0.f : Vn;
    sout[j] = sp ? (ushort)0x3F80 : (ushort)0;
    oout[j] = sp ? 1.f : 0.f;
    if (sp) { csum += wnn; cnt++; }
  }
  *(float4*)(V + e) = make_float4(vout[0], vout[1], vout[2], vout[3]);
  ushort4 sq; sq.x = sout[0]; sq.y = sout[1]; sq.z = sout[2]; sq.w = sout[3];
  *(ushort4*)(spout + e) = sq;
  if (LAST && t == T_STEPS) *(float4*)(outF + e) = make_float4(oout[0], oout[1], oout[2], oout[3]);
  int f = 17 - t; if (f > 10) f = 10;
  cost_accum_raw(csum * (float)f, cnt, cost, tot);
  (void)tf;
}

// ---------------- L0 elementwise LIF (4 elems/thread) ----------------

__device__ void l0_role(const StepParams& p, int bid, int s) {
  const int tid = threadIdx.x;
  int e = (bid * 256 + tid) * 4;          // 512 blocks cover 524288
  int n0i = e & 2047;
  const ushort* pr = ((s - 1) & 1) ? p.sp0b : p.sp0a;
  ushort* so = (s & 1) ? p.sp0b : p.sp0a;
  size_t off = (size_t)(s - 1) * 524288 + e;

  float4 bb  = *(const float4*)(p.base0 + e);
  float4 c4  = *(const float4*)(p.cn0 + off);
  float4 t4  = *(const float4*)(p.tn0 + off);
  float4 th4 = *(const float4*)(p.th0 + n0i);
  float4 wn4 = *(const float4*)(p.wn0 + n0i);
  float4 vv  = (s == 1) ? make_float4(0.f, 0.f, 0.f, 0.f) : *(const float4*)(p.V0 + e);
  ushort prv[4] = {0, 0, 0, 0};
  if (s > 1) { ushort4 pq = *(const ushort4*)(pr + e); prv[0] = pq.x; prv[1] = pq.y; prv[2] = pq.z; prv[3] = pq.w; }

  float bbv[4] = {bb.x, bb.y, bb.z, bb.w};
  float vvv[4] = {vv.x, vv.y, vv.z, vv.w};
  float cnv[4] = {c4.x, c4.y, c4.z, c4.w};
  float tnv[4] = {t4.x, t4.y, t4.z, t4.w};
  float thv[4] = {th4.x, th4.y, th4.z, th4.w};
  float wnq[4] = {wn4.x, wn4.y, wn4.z, wn4.w};
  float tf = (float)s;
  float csum = 0.f; int cnt = 0;
  ushort sout[4]; float vout[4];
  #pragma unroll
  for (int j = 0; j < 4; ++j) {
    float wnn = wnq[j];
    float cur = bbv[j] + cnv[j] * (0.05f * wnn);
    bool refrac = (s > 1) && (prv[j] != 0);
    float Vn = refrac ? vvv[j] : (0.95f * vvv[j] + cur);
    float thr = thv[j] + tnv[j] * 0.1f;
    bool sp = (!refrac) && (Vn > thr);
    vout[j] = sp ? 0.f : Vn;
    sout[j] = sp ? (ushort)0x3F80 : (ushort)0;
    if (sp) { csum += wnn; cnt++; }
  }
  *(float4*)(p.V0 + e) = make_float4(vout[0], vout[1], vout[2], vout[3]);
  ushort4 sq; sq.x = sout[0]; sq.y = sout[1]; sq.z = sout[2]; sq.w = sout[3];
  *(ushort4*)(so + e) = sq;
  int f = 17 - s; if (f > 10) f = 10;
  cost_accum_raw(csum * (float)f, cnt, p.cost, p.tot);
  (void)tf;
}

// ---------------- phase kernel: 5 roles, all deps cross-dispatch ----------------

__global__ __launch_bounds__(256) void phase_kernel(StepParams p, int d) {
  const int bid = blockIdx.x;
  if (bid < 256) {
    int t = d;                                   // L1 partial GEMM
    if (t >= 1 && t <= 16) {
      const ushort* A = (t & 1) ? p.sp0b : p.sp0a;
      float* P = p.P1 + (size_t)(t & 1) * 1048576;
      gemm_partial<2048, 1024>(A, p.w1b, P, bid & 63, bid >> 6);
    }
  } else if (bid < 512) {
    int t = d - 1;                               // L1 LIF from partials
    if (t >= 1 && t <= 16) {
      const float* P = p.P1 + (size_t)(t & 1) * 1048576;
      const ushort* pr = ((t - 1) & 1) ? p.sp1b : p.sp1a;
      ushort* so = (t & 1) ? p.sp1b : p.sp1a;
      lif_partial<1024, false>(P, pr, so, p.cn1, p.tn1, p.th1, p.wn1, p.V1, nullptr,
                               p.cost, p.tot, t, bid - 256);
    }
  } else if (bid < 640) {
    int t2 = d - 2;                              // L2 partial GEMM
    if (t2 >= 1 && t2 <= 16) {
      const ushort* A = (t2 & 1) ? p.sp1b : p.sp1a;
      float* P = p.P2 + (size_t)(t2 & 1) * 524288;
      int b2 = bid - 512;
      gemm_partial<1024, 512>(A, p.w2b, P, b2 & 31, b2 >> 5);
    }
  } else if (bid < 768) {
    int t2 = d - 3;                              // L2 LIF from partials (+ out at t=16)
    if (t2 >= 1 && t2 <= 16) {
      const float* P = p.P2 + (size_t)(t2 & 1) * 524288;
      const ushort* pr = ((t2 - 1) & 1) ? p.sp2b : p.sp2a;
      ushort* so = (t2 & 1) ? p.sp2b : p.sp2a;
      lif_partial<512, true>(P, pr, so, p.cn2, p.tn2, p.th2, p.wn2, p.V2, p.out,
                             p.cost, p.tot, t2, bid - 640);
    }
  } else {
    int s = d + 1;                               // L0 elementwise LIF
    if (s <= 16) l0_role(p, bid - 768, s);
  }
}

// ---------------- finalize ----------------

__global__ __launch_bounds__(64) void finalize_kernel(const float* __restrict__ cost,
                                                      const float* __restrict__ tot,
                                                      float* __restrict__ out) {
  if (threadIdx.x == 0) {
    float c = *cost;
    float p1 = *tot / 14680064.f;   // T*B*(2048+1024+512)
    float p0 = 1.f - p1;
    float ent = -(p1 * log2f(p1 + 1e-12f) + p0 * log2f(p0 + 1e-12f));
    out[131072] = c;
    out[131073] = ent;
  }
}

// ---------------- launch ----------------

extern "C" void kernel_launch(void* const* d_in, const int* in_sizes, int n_in,
                              void* d_out, int out_size, void* d_ws, size_t ws_size,
                              hipStream_t stream) {
  const float* inputs = (const float*)d_in[0];
  const float* w0  = (const float*)d_in[1];
  const float* th0 = (const float*)d_in[2];
  const float* cn0 = (const float*)d_in[3];
  const float* tn0 = (const float*)d_in[4];
  const float* w1  = (const float*)d_in[5];
  const float* th1 = (const float*)d_in[6];
  const float* cn1 = (const float*)d_in[7];
  const float* tn1 = (const float*)d_in[8];
  const float* w2  = (const float*)d_in[9];
  const float* th2 = (const float*)d_in[10];
  const float* cn2 = (const float*)d_in[11];
  const float* tn2 = (const float*)d_in[12];
  float* out = (float*)d_out;
  float* ws  = (float*)d_ws;

  // workspace layout (float slots), total ~6.82M floats = ~26 MB
  float* wn    = ws;                    // 3584: wn0[2048] wn1[1024] wn2[512]
  float* cost  = ws + 3584;
  float* tot   = ws + 3585;
  float* base0 = ws + 4096;             // 524288
  float* V0    = base0 + 524288;        // 524288
  float* V1    = V0 + 524288;           // 262144
  float* V2    = V1 + 262144;           // 131072
  ushort* w1b  = (ushort*)(V2 + 131072);        // 2097152 ushort
  ushort* w2b  = w1b + 2097152;                 // 524288 ushort
  ushort* sp0a = w2b + 524288;                  // 524288 ushort each
  ushort* sp0b = sp0a + 524288;
  ushort* sp1a = sp0b + 524288;                 // 262144 ushort each
  ushort* sp1b = sp1a + 262144;
  ushort* sp2a = sp1b + 262144;                 // 131072 ushort each
  ushort* sp2b = sp2a + 131072;
  float* P1 = (float*)(sp2b + 131072);          // 2097152 floats (both parities)
  float* P2 = P1 + 2097152;                     // 1048576 floats

  wnorm_kernel<<<3584, 64, 0, stream>>>(w0, w1, w2, wn, cost, tot);
  convert_w_kernel<<<1280, 256, 0, stream>>>(w1, w2, w1b, w2b);
  base0_mfma_kernel<<<dim3(4, 32), 256, 0, stream>>>(inputs, w0, base0);

  StepParams p;
  p.base0 = base0; p.cn0 = cn0; p.tn0 = tn0; p.th0 = th0; p.wn0 = wn;
  p.V0 = V0; p.sp0a = sp0a; p.sp0b = sp0b;
  p.w1b = w1b; p.cn1 = cn1; p.tn1 = tn1; p.th1 = th1; p.wn1 = wn + 2048;
  p.V1 = V1; p.sp1a = sp1a; p.sp1b = sp1b;
  p.w2b = w2b; p.cn2 = cn2; p.tn2 = tn2; p.th2 = th2; p.wn2 = wn + 3072;
  p.V2 = V2; p.sp2a = sp2a; p.sp2b = sp2b;
  p.P1 = P1; p.P2 = P2;
  p.out = out; p.cost = cost; p.tot = tot;

  for (int d = 0; d <= 19; ++d) {
    phase_kernel<<<1280, 256, 0, stream>>>(p, d);
  }
  finalize_kernel<<<1, 64, 0, stream>>>(cost, tot, out);
}

// Round 7
// 463.537 us; speedup vs baseline: 2.7750x; 1.5972x over previous
//
#include <hip/hip_runtime.h>
#include <math.h>

// NeuromorphicPrivacyNetwork: 3-layer LIF SNN, T=16, B=256, sizes 1024->2048->1024->512.
// Round-7: round-6 K-split partial pipeline + REMOVE the same-cacheline atomic chain
// (2560 serialized atomicAdds/dispatch ~= 30us critical path). Each block accumulates
// cost/count into its own float2 bucket (non-atomic, distinct addr); finalize reduces.
//   - 20 pipelined dispatches; phase d roles (all deps cross-dispatch):
//       bid [0,256)    L1-gemm-partial(t=d)
//       bid [256,512)  L1-lif(t=d-1)
//       bid [512,640)  L2-gemm-partial(t=d-2)
//       bid [640,768)  L2-lif(t=d-3)  (+ out0 at t=16)
//       bid [768,1280) L0-lif(s=d+1)
//   - no LDS in phase kernel; W1/W2 bf16; spikes bf16 {0,1}; partials fp32 slice-indexed
//   - trailing-window factor min(10, 17-t) folded into per-spike cost

#define B 256
#define T_STEPS 16

typedef short short8 __attribute__((ext_vector_type(8)));
typedef float floatx4 __attribute__((ext_vector_type(4)));

__device__ inline ushort f2bf(float x) {
  unsigned int u = __float_as_uint(x);
  unsigned int r = (u + 0x7FFFu + ((u >> 16) & 1u)) >> 16;
  return (ushort)r;
}
__device__ inline float bf2f(ushort h) {
  return __uint_as_float(((unsigned int)h) << 16);
}
__device__ inline floatx4 mfma16(short8 a, short8 b, floatx4 c) {
  return __builtin_amdgcn_mfma_f32_16x16x32_bf16(a, b, c, 0, 0, 0);
}

// stage 16 fp32 -> hi/lo bf16 pairs into LDS (base0 setup GEMM only)
__device__ inline void stage_split16(const float* __restrict__ src, ushort* dsth, ushort* dstl) {
  float fv[16];
  #pragma unroll
  for (int i = 0; i < 4; ++i) *(float4*)&fv[4 * i] = *(const float4*)(src + 4 * i);
  unsigned int ph[8], pl[8];
  #pragma unroll
  for (int i = 0; i < 8; ++i) {
    ushort h0 = f2bf(fv[2 * i]);
    ushort l0 = f2bf(fv[2 * i] - bf2f(h0));
    ushort h1 = f2bf(fv[2 * i + 1]);
    ushort l1 = f2bf(fv[2 * i + 1] - bf2f(h1));
    ph[i] = (unsigned int)h0 | ((unsigned int)h1 << 16);
    pl[i] = (unsigned int)l0 | ((unsigned int)l1 << 16);
  }
  *(uint4*)dsth       = make_uint4(ph[0], ph[1], ph[2], ph[3]);
  *(uint4*)(dsth + 8) = make_uint4(ph[4], ph[5], ph[6], ph[7]);
  *(uint4*)dstl       = make_uint4(pl[0], pl[1], pl[2], pl[3]);
  *(uint4*)(dstl + 8) = make_uint4(pl[4], pl[5], pl[6], pl[7]);
}

// block-reduce then NON-ATOMIC accumulate into this block's private bucket.
// Same bid across successive dispatches is ordered by the stream -> no race.
__device__ inline void cost_accum_bucket(float csum, int cnt, float2* __restrict__ cbuf) {
  #pragma unroll
  for (int off = 32; off > 0; off >>= 1) {
    csum += __shfl_down(csum, off);
    cnt  += __shfl_down(cnt, off);
  }
  __shared__ float sc[4];
  __shared__ int   si[4];
  int wid = threadIdx.x >> 6;
  if ((threadIdx.x & 63) == 0) { sc[wid] = csum; si[wid] = cnt; }
  __syncthreads();
  if (threadIdx.x == 0) {
    float c = sc[0] + sc[1] + sc[2] + sc[3];
    int   k = si[0] + si[1] + si[2] + si[3];
    float2 v = cbuf[blockIdx.x];
    v.x += c * 0.01f;            // per-spike cost = 0.1 * fac/10 * wn = 0.01*fac*wn
    v.y += (float)k;
    cbuf[blockIdx.x] = v;
  }
}

// ---------------- weight row norms ----------------

__global__ __launch_bounds__(64) void wnorm_kernel(const float* __restrict__ w0,
                                                   const float* __restrict__ w1,
                                                   const float* __restrict__ w2,
                                                   float* __restrict__ wn) {
  int r = blockIdx.x;  // 0..3583
  const float* row; int K;
  if (r < 2048)      { row = w0 + (size_t)r * 1024;          K = 1024; }
  else if (r < 3072) { row = w1 + (size_t)(r - 2048) * 2048; K = 2048; }
  else               { row = w2 + (size_t)(r - 3072) * 1024; K = 1024; }
  float ss = 0.f;
  for (int k = threadIdx.x; k < K; k += 64) { float x = row[k]; ss += x * x; }
  #pragma unroll
  for (int off = 32; off > 0; off >>= 1) ss += __shfl_down(ss, off);
  if (threadIdx.x == 0) wn[r] = sqrtf(ss);
}

// ---------------- convert W1,W2 -> bf16 (+ zero the cost buckets) ----------------

__global__ __launch_bounds__(256) void convert_w_kernel(const float* __restrict__ w1,
                                                        const float* __restrict__ w2,
                                                        ushort* __restrict__ w1b,
                                                        ushort* __restrict__ w2b,
                                                        float2* __restrict__ cbuf) {
  if (blockIdx.x < 5) {   // 5*256 = 1280 buckets zeroed
    cbuf[blockIdx.x * 256 + threadIdx.x] = make_float2(0.f, 0.f);
  }
  int i = (blockIdx.x * 256 + threadIdx.x) * 8;   // 1280 blocks -> 2621440 elems
  const float* src; ushort* dst;
  if (i < 2097152) { src = w1 + i; dst = w1b + i; }
  else             { src = w2 + (i - 2097152); dst = w2b + (i - 2097152); }
  float4 a = *(const float4*)src;
  float4 b = *(const float4*)(src + 4);
  unsigned int p0 = (unsigned int)f2bf(a.x) | ((unsigned int)f2bf(a.y) << 16);
  unsigned int p1 = (unsigned int)f2bf(a.z) | ((unsigned int)f2bf(a.w) << 16);
  unsigned int p2 = (unsigned int)f2bf(b.x) | ((unsigned int)f2bf(b.y) << 16);
  unsigned int p3 = (unsigned int)f2bf(b.z) | ((unsigned int)f2bf(b.w) << 16);
  *(uint4*)dst = make_uint4(p0, p1, p2, p3);
}

// ---------------- base0 = inputs @ w0^T via split MFMA (one-time) ----------------

__global__ __launch_bounds__(256) void base0_mfma_kernel(const float* __restrict__ A,  // [256][1024]
                                                         const float* __restrict__ W,  // [2048][1024]
                                                         float* __restrict__ C) {      // [256][2048]
  __shared__ ushort Ah[64][72], Al[64][72], Bh[64][72], Bl[64][72];
  const int tid = threadIdx.x;
  const int m0 = blockIdx.x * 64;
  const int n0 = blockIdx.y * 64;
  const int lane = tid & 63, wv = tid >> 6;
  const int wm = wv & 1, wn2 = wv >> 1;
  const int l15 = lane & 15, quad = lane >> 4;
  const int sr = tid >> 2, scol = (tid & 3) * 16;

  floatx4 acc[2][2];
  #pragma unroll
  for (int i = 0; i < 2; ++i)
    #pragma unroll
    for (int j = 0; j < 2; ++j) acc[i][j] = (floatx4){0.f, 0.f, 0.f, 0.f};

  for (int k0 = 0; k0 < 1024; k0 += 64) {
    stage_split16(A + (size_t)(m0 + sr) * 1024 + k0 + scol, &Ah[sr][scol], &Al[sr][scol]);
    stage_split16(W + (size_t)(n0 + sr) * 1024 + k0 + scol, &Bh[sr][scol], &Bl[sr][scol]);
    __syncthreads();
    #pragma unroll
    for (int ks = 0; ks < 2; ++ks) {
      short8 ah[2], al[2], bh[2], bl[2];
      #pragma unroll
      for (int s = 0; s < 2; ++s) {
        ah[s] = *(const short8*)&Ah[32 * wm + 16 * s + l15][ks * 32 + quad * 8];
        al[s] = *(const short8*)&Al[32 * wm + 16 * s + l15][ks * 32 + quad * 8];
        bh[s] = *(const short8*)&Bh[32 * wn2 + 16 * s + l15][ks * 32 + quad * 8];
        bl[s] = *(const short8*)&Bl[32 * wn2 + 16 * s + l15][ks * 32 + quad * 8];
      }
      #pragma unroll
      for (int sm = 0; sm < 2; ++sm)
        #pragma unroll
        for (int sn = 0; sn < 2; ++sn) {
          acc[sm][sn] = mfma16(ah[sm], bh[sn], acc[sm][sn]);
          acc[sm][sn] = mfma16(ah[sm], bl[sn], acc[sm][sn]);
          acc[sm][sn] = mfma16(al[sm], bh[sn], acc[sm][sn]);
        }
    }
    __syncthreads();
  }
  #pragma unroll
  for (int sm = 0; sm < 2; ++sm)
    #pragma unroll
    for (int sn = 0; sn < 2; ++sn)
      #pragma unroll
      for (int r = 0; r < 4; ++r) {
        int m = m0 + 32 * wm + 16 * sm + quad * 4 + r;
        int n = n0 + 32 * wn2 + 16 * sn + l15;
        C[(size_t)m * 2048 + n] = acc[sm][sn][r];
      }
}

// ---------------- params ----------------

struct StepParams {
  const float* base0; const float* cn0; const float* tn0; const float* th0; const float* wn0;
  float* V0; ushort* sp0a; ushort* sp0b;
  const ushort* w1b; const float* cn1; const float* tn1; const float* th1; const float* wn1;
  float* V1; ushort* sp1a; ushort* sp1b;
  const ushort* w2b; const float* cn2; const float* tn2; const float* th2; const float* wn2;
  float* V2; ushort* sp2a; ushort* sp2b;
  float* P1; float* P2;   // fp32 partials: P1[2][4][256][1024], P2[2][4][256][512]
  float* out; float2* cbuf;
};

// ---------------- partial GEMM: 64x64 tile over one K-slice, direct-global frags ----------

template<int K>
__device__ inline void ld_frags(const ushort* __restrict__ Abase,
                                const ushort* __restrict__ Wbase,
                                int l15, int k0, uint4 fa[2][2], uint4 fb[2][2]) {
  #pragma unroll
  for (int ks = 0; ks < 2; ++ks)
    #pragma unroll
    for (int s = 0; s < 2; ++s) {
      fa[ks][s] = *(const uint4*)(Abase + (size_t)(16 * s + l15) * K + k0 + ks * 32);
      fb[ks][s] = *(const uint4*)(Wbase + (size_t)(16 * s + l15) * K + k0 + ks * 32);
    }
}

template<int K, int N>
__device__ void gemm_partial(const ushort* __restrict__ A,   // [256][K] bf16 spikes
                             const ushort* __restrict__ W,   // [N][K] bf16
                             float* __restrict__ P,          // [4][256][N] fp32 (this parity)
                             int tile, int slice) {
  constexpr int SL = K / 4;           // K-slice length
  const int ks0 = slice * SL;
  const int tid = threadIdx.x;
  const int m0 = (tile & 3) * 64, n0 = (tile >> 2) * 64;
  const int lane = tid & 63, wv = tid >> 6;
  const int wm = wv & 1, wn2 = wv >> 1;
  const int l15 = lane & 15, quad = lane >> 4;

  const ushort* Abase = A + (size_t)(m0 + 32 * wm) * K + ks0 + quad * 8;
  const ushort* Wbase = W + (size_t)(n0 + 32 * wn2) * K + ks0 + quad * 8;

  floatx4 acc[2][2];
  #pragma unroll
  for (int i = 0; i < 2; ++i)
    #pragma unroll
    for (int j = 0; j < 2; ++j) acc[i][j] = (floatx4){0.f, 0.f, 0.f, 0.f};

  uint4 fa[2][2], fb[2][2];
  ld_frags<K>(Abase, Wbase, l15, 0, fa, fb);
  for (int k0 = 0; k0 < SL; k0 += 64) {
    uint4 na[2][2], nb[2][2];
    if (k0 + 64 < SL) ld_frags<K>(Abase, Wbase, l15, k0 + 64, na, nb);
    #pragma unroll
    for (int ks = 0; ks < 2; ++ks)
      #pragma unroll
      for (int sm = 0; sm < 2; ++sm)
        #pragma unroll
        for (int sn = 0; sn < 2; ++sn)
          acc[sm][sn] = mfma16(*(const short8*)&fa[ks][sm], *(const short8*)&fb[ks][sn], acc[sm][sn]);
    #pragma unroll
    for (int ks = 0; ks < 2; ++ks)
      #pragma unroll
      for (int s = 0; s < 2; ++s) { fa[ks][s] = na[ks][s]; fb[ks][s] = nb[ks][s]; }
  }

  float* Ps = P + (size_t)slice * 256 * N;
  #pragma unroll
  for (int sm = 0; sm < 2; ++sm)
    #pragma unroll
    for (int sn = 0; sn < 2; ++sn)
      #pragma unroll
      for (int r = 0; r < 4; ++r) {
        int m = m0 + 32 * wm + 16 * sm + quad * 4 + r;
        int n = n0 + 32 * wn2 + 16 * sn + l15;
        Ps[(size_t)m * N + n] = acc[sm][sn][r];
      }
}

// ---------------- LIF from 4 fp32 partials + noise ----------------

template<int N, bool LAST>
__device__ void lif_partial(const float* __restrict__ P,     // [4][256][N] (this parity)
                            const ushort* __restrict__ sppr, // [256][N] prev spikes
                            ushort* __restrict__ spout,      // [256][N]
                            const float* __restrict__ cn, const float* __restrict__ tn,
                            const float* __restrict__ th, const float* __restrict__ wnv,
                            float* __restrict__ V, float* __restrict__ outF,
                            float2* __restrict__ cbuf, int t, int bid) {
  constexpr int SZ = 256 * N;
  int e = (bid * 256 + threadIdx.x) * 4;
  int n = e & (N - 1);
  size_t off = (size_t)(t - 1) * SZ + e;

  float4 a0 = *(const float4*)(P + e);
  float4 a1 = *(const float4*)(P + SZ + e);
  float4 a2 = *(const float4*)(P + 2 * SZ + e);
  float4 a3 = *(const float4*)(P + 3 * SZ + e);
  float4 c4  = *(const float4*)(cn + off);
  float4 t4  = *(const float4*)(tn + off);
  float4 th4 = *(const float4*)(th + n);
  float4 wn4 = *(const float4*)(wnv + n);
  float4 vv  = (t == 1) ? make_float4(0.f, 0.f, 0.f, 0.f) : *(const float4*)(V + e);
  ushort prv[4] = {0, 0, 0, 0};
  if (t > 1) { ushort4 pq = *(const ushort4*)(sppr + e); prv[0] = pq.x; prv[1] = pq.y; prv[2] = pq.z; prv[3] = pq.w; }

  float accv[4] = {a0.x + a1.x + a2.x + a3.x, a0.y + a1.y + a2.y + a3.y,
                   a0.z + a1.z + a2.z + a3.z, a0.w + a1.w + a2.w + a3.w};
  float vvv[4] = {vv.x, vv.y, vv.z, vv.w};
  float cnv[4] = {c4.x, c4.y, c4.z, c4.w};
  float tnv[4] = {t4.x, t4.y, t4.z, t4.w};
  float thv[4] = {th4.x, th4.y, th4.z, th4.w};
  float wnq[4] = {wn4.x, wn4.y, wn4.z, wn4.w};
  float csum = 0.f; int cnt = 0;
  ushort sout[4]; float vout[4]; float oout[4];
  #pragma unroll
  for (int j = 0; j < 4; ++j) {
    float wnn = wnq[j];
    float cur = accv[j] + cnv[j] * (0.05f * wnn);
    bool refrac = (t > 1) && (prv[j] != 0);
    float Vn = refrac ? vvv[j] : (0.95f * vvv[j] + cur);
    float thr = thv[j] + tnv[j] * 0.1f;
    bool sp = (!refrac) && (Vn > thr);
    vout[j] = sp ? 0.f : Vn;
    sout[j] = sp ? (ushort)0x3F80 : (ushort)0;
    oout[j] = sp ? 1.f : 0.f;
    if (sp) { csum += wnn; cnt++; }
  }
  *(float4*)(V + e) = make_float4(vout[0], vout[1], vout[2], vout[3]);
  ushort4 sq; sq.x = sout[0]; sq.y = sout[1]; sq.z = sout[2]; sq.w = sout[3];
  *(ushort4*)(spout + e) = sq;
  if (LAST && t == T_STEPS) *(float4*)(outF + e) = make_float4(oout[0], oout[1], oout[2], oout[3]);
  int f = 17 - t; if (f > 10) f = 10;
  cost_accum_bucket(csum * (float)f, cnt, cbuf);
}

// ---------------- L0 elementwise LIF (4 elems/thread) ----------------

__device__ void l0_role(const StepParams& p, int bid, int s) {
  const int tid = threadIdx.x;
  int e = (bid * 256 + tid) * 4;          // 512 blocks cover 524288
  int n0i = e & 2047;
  const ushort* pr = ((s - 1) & 1) ? p.sp0b : p.sp0a;
  ushort* so = (s & 1) ? p.sp0b : p.sp0a;
  size_t off = (size_t)(s - 1) * 524288 + e;

  float4 bb  = *(const float4*)(p.base0 + e);
  float4 c4  = *(const float4*)(p.cn0 + off);
  float4 t4  = *(const float4*)(p.tn0 + off);
  float4 th4 = *(const float4*)(p.th0 + n0i);
  float4 wn4 = *(const float4*)(p.wn0 + n0i);
  float4 vv  = (s == 1) ? make_float4(0.f, 0.f, 0.f, 0.f) : *(const float4*)(p.V0 + e);
  ushort prv[4] = {0, 0, 0, 0};
  if (s > 1) { ushort4 pq = *(const ushort4*)(pr + e); prv[0] = pq.x; prv[1] = pq.y; prv[2] = pq.z; prv[3] = pq.w; }

  float bbv[4] = {bb.x, bb.y, bb.z, bb.w};
  float vvv[4] = {vv.x, vv.y, vv.z, vv.w};
  float cnv[4] = {c4.x, c4.y, c4.z, c4.w};
  float tnv[4] = {t4.x, t4.y, t4.z, t4.w};
  float thv[4] = {th4.x, th4.y, th4.z, th4.w};
  float wnq[4] = {wn4.x, wn4.y, wn4.z, wn4.w};
  float csum = 0.f; int cnt = 0;
  ushort sout[4]; float vout[4];
  #pragma unroll
  for (int j = 0; j < 4; ++j) {
    float wnn = wnq[j];
    float cur = bbv[j] + cnv[j] * (0.05f * wnn);
    bool refrac = (s > 1) && (prv[j] != 0);
    float Vn = refrac ? vvv[j] : (0.95f * vvv[j] + cur);
    float thr = thv[j] + tnv[j] * 0.1f;
    bool sp = (!refrac) && (Vn > thr);
    vout[j] = sp ? 0.f : Vn;
    sout[j] = sp ? (ushort)0x3F80 : (ushort)0;
    if (sp) { csum += wnn; cnt++; }
  }
  *(float4*)(p.V0 + e) = make_float4(vout[0], vout[1], vout[2], vout[3]);
  ushort4 sq; sq.x = sout[0]; sq.y = sout[1]; sq.z = sout[2]; sq.w = sout[3];
  *(ushort4*)(so + e) = sq;
  int f = 17 - s; if (f > 10) f = 10;
  cost_accum_bucket(csum * (float)f, cnt, p.cbuf);
}

// ---------------- phase kernel: 5 roles, all deps cross-dispatch ----------------

__global__ __launch_bounds__(256) void phase_kernel(StepParams p, int d) {
  const int bid = blockIdx.x;
  if (bid < 256) {
    int t = d;                                   // L1 partial GEMM
    if (t >= 1 && t <= 16) {
      const ushort* A = (t & 1) ? p.sp0b : p.sp0a;
      float* P = p.P1 + (size_t)(t & 1) * 1048576;
      gemm_partial<2048, 1024>(A, p.w1b, P, bid & 63, bid >> 6);
    }
  } else if (bid < 512) {
    int t = d - 1;                               // L1 LIF from partials
    if (t >= 1 && t <= 16) {
      const float* P = p.P1 + (size_t)(t & 1) * 1048576;
      const ushort* pr = ((t - 1) & 1) ? p.sp1b : p.sp1a;
      ushort* so = (t & 1) ? p.sp1b : p.sp1a;
      lif_partial<1024, false>(P, pr, so, p.cn1, p.tn1, p.th1, p.wn1, p.V1, nullptr,
                               p.cbuf, t, bid - 256);
    }
  } else if (bid < 640) {
    int t2 = d - 2;                              // L2 partial GEMM
    if (t2 >= 1 && t2 <= 16) {
      const ushort* A = (t2 & 1) ? p.sp1b : p.sp1a;
      float* P = p.P2 + (size_t)(t2 & 1) * 524288;
      int b2 = bid - 512;
      gemm_partial<1024, 512>(A, p.w2b, P, b2 & 31, b2 >> 5);
    }
  } else if (bid < 768) {
    int t2 = d - 3;                              // L2 LIF from partials (+ out at t=16)
    if (t2 >= 1 && t2 <= 16) {
      const float* P = p.P2 + (size_t)(t2 & 1) * 524288;
      const ushort* pr = ((t2 - 1) & 1) ? p.sp2b : p.sp2a;
      ushort* so = (t2 & 1) ? p.sp2b : p.sp2a;
      lif_partial<512, true>(P, pr, so, p.cn2, p.tn2, p.th2, p.wn2, p.V2, p.out,
                             p.cbuf, t2, bid - 640);
    }
  } else {
    int s = d + 1;                               // L0 elementwise LIF
    if (s <= 16) l0_role(p, bid - 768, s);
  }
}

// ---------------- finalize: reduce 1280 buckets -> cost, entropy ----------------

__global__ __launch_bounds__(256) void finalize_kernel(const float2* __restrict__ cbuf,
                                                       float* __restrict__ out) {
  float c = 0.f, k = 0.f;
  for (int i = threadIdx.x; i < 1280; i += 256) {
    float2 v = cbuf[i];
    c += v.x; k += v.y;
  }
  #pragma unroll
  for (int off = 32; off > 0; off >>= 1) {
    c += __shfl_down(c, off);
    k += __shfl_down(k, off);
  }
  __shared__ float sc[4], sk[4];
  int wid = threadIdx.x >> 6;
  if ((threadIdx.x & 63) == 0) { sc[wid] = c; sk[wid] = k; }
  __syncthreads();
  if (threadIdx.x == 0) {
    float cost = sc[0] + sc[1] + sc[2] + sc[3];
    float tot  = sk[0] + sk[1] + sk[2] + sk[3];
    float p1 = tot / 14680064.f;   // T*B*(2048+1024+512)
    float p0 = 1.f - p1;
    float ent = -(p1 * log2f(p1 + 1e-12f) + p0 * log2f(p0 + 1e-12f));
    out[131072] = cost;
    out[131073] = ent;
  }
}

// ---------------- launch ----------------

extern "C" void kernel_launch(void* const* d_in, const int* in_sizes, int n_in,
                              void* d_out, int out_size, void* d_ws, size_t ws_size,
                              hipStream_t stream) {
  const float* inputs = (const float*)d_in[0];
  const float* w0  = (const float*)d_in[1];
  const float* th0 = (const float*)d_in[2];
  const float* cn0 = (const float*)d_in[3];
  const float* tn0 = (const float*)d_in[4];
  const float* w1  = (const float*)d_in[5];
  const float* th1 = (const float*)d_in[6];
  const float* cn1 = (const float*)d_in[7];
  const float* tn1 = (const float*)d_in[8];
  const float* w2  = (const float*)d_in[9];
  const float* th2 = (const float*)d_in[10];
  const float* cn2 = (const float*)d_in[11];
  const float* tn2 = (const float*)d_in[12];
  float* out = (float*)d_out;
  float* ws  = (float*)d_ws;

  // workspace layout (float slots), total ~6.83M floats = ~26 MB
  float* wn    = ws;                    // 3584: wn0[2048] wn1[1024] wn2[512]
  float* base0 = ws + 4096;             // 524288
  float* V0    = base0 + 524288;        // 524288
  float* V1    = V0 + 524288;           // 262144
  float* V2    = V1 + 262144;           // 131072
  ushort* w1b  = (ushort*)(V2 + 131072);        // 2097152 ushort
  ushort* w2b  = w1b + 2097152;                 // 524288 ushort
  ushort* sp0a = w2b + 524288;                  // 524288 ushort each
  ushort* sp0b = sp0a + 524288;
  ushort* sp1a = sp0b + 524288;                 // 262144 ushort each
  ushort* sp1b = sp1a + 262144;
  ushort* sp2a = sp1b + 262144;                 // 131072 ushort each
  ushort* sp2b = sp2a + 131072;
  float* P1 = (float*)(sp2b + 131072);          // 2097152 floats (both parities)
  float* P2 = P1 + 2097152;                     // 1048576 floats
  float2* cbuf = (float2*)(P2 + 1048576);       // 1280 float2

  wnorm_kernel<<<3584, 64, 0, stream>>>(w0, w1, w2, wn);
  convert_w_kernel<<<1280, 256, 0, stream>>>(w1, w2, w1b, w2b, cbuf);
  base0_mfma_kernel<<<dim3(4, 32), 256, 0, stream>>>(inputs, w0, base0);

  StepParams p;
  p.base0 = base0; p.cn0 = cn0; p.tn0 = tn0; p.th0 = th0; p.wn0 = wn;
  p.V0 = V0; p.sp0a = sp0a; p.sp0b = sp0b;
  p.w1b = w1b; p.cn1 = cn1; p.tn1 = tn1; p.th1 = th1; p.wn1 = wn + 2048;
  p.V1 = V1; p.sp1a = sp1a; p.sp1b = sp1b;
  p.w2b = w2b; p.cn2 = cn2; p.tn2 = tn2; p.th2 = th2; p.wn2 = wn + 3072;
  p.V2 = V2; p.sp2a = sp2a; p.sp2b = sp2b;
  p.P1 = P1; p.P2 = P2;
  p.out = out; p.cbuf = cbuf;

  for (int d = 0; d <= 19; ++d) {
    phase_kernel<<<1280, 256, 0, stream>>>(p, d);
  }
  finalize_kernel<<<1, 256, 0, stream>>>(cbuf, out);
}